// Round 7
// baseline (297.703 us; speedup 1.0000x reference)
//
#include <hip/hip_runtime.h>

#define K_CODES 1024
#define D_DIM 128
#define N_ROWS 65536
#define DECAY_F 0.99f
#define OMD_F 0.01f
#define EPS_F 1e-5f

#define EPAD 136                        // padded fp16 row (272 B)
#define CH_CODES 64                     // codes per LDS chunk
#define CH64_U (2 * CH_CODES * EPAD)    // 17408 ushorts = 34816 B (hi+lo)
#define CH_LO 8704                      // ushort offset of lo image in chunk
#define NT 2                            // row tiles per wave (32 rows/wave)
#define QCODES 256                      // codes per block (quarter split)
#define SEG_TILE 64
#define RESCUE_EPS 1e-3f

// ---------------------------------------------------------------------------
// ws layout (float units). [0, WS_ZERO_END) zeroed by vq_prep every call.
//   cnt[1024] | loss[1] pad[3] | be[131072] || enorm | smoothed | cursor |
//   fidx[65536] | znorm[65536] | cand u32[65536][4][4] (bucket/scode alias
//   inside cand: scatter runs after finish) | eimg ushort[16][2][64][136]
// ---------------------------------------------------------------------------
#define WS_CNT     0
#define WS_LOSS    1024
#define WS_BE      1028
#define WS_ZERO_END (1028 + 131072)     // 132100
#define WS_ENORM   132100
#define WS_SMOOTH  133124
#define WS_CUR     134148
#define WS_FIDX    135172
#define WS_ZNORM   200708
#define WS_CAND    266244               // 1048576 floats
#define WS_BUCKET  266244               // aliases cand (safe: after finish)
#define WS_SCODE   331780               // aliases cand
#define WS_EIMG    1314820              // 139264 floats of ushort image

typedef _Float16 h8_t __attribute__((ext_vector_type(8)));
typedef float    f4_t __attribute__((ext_vector_type(4)));

__device__ inline unsigned short f2h_bits(float f) {
    _Float16 h = (_Float16)f;
    return __builtin_bit_cast(unsigned short, h);
}
__device__ inline float h_bits2f(unsigned short u) {
    _Float16 h = __builtin_bit_cast(_Float16, u);
    return (float)h;
}

// async global->LDS, 16 B/lane (HW: lds dest = uniform base + lane*16)
__device__ inline void gld16(const void* g, void* l) {
    __builtin_amdgcn_global_load_lds(
        (const __attribute__((address_space(1))) void*)g,
        (__attribute__((address_space(3))) void*)l, 16, 0, 0);
}

// ---------------------------------------------------------------------------
// Prep: zero cnt/loss/be + enorm + fp16 hi/lo split image. grid 128 x 256.
// ---------------------------------------------------------------------------
__global__ void vq_prep(const float* __restrict__ emb, float* __restrict__ ws,
                        float* __restrict__ enorm, unsigned short* __restrict__ eimg) {
    int t = blockIdx.x * blockDim.x + threadIdx.x;   // 32768
    for (int i = t; i < WS_ZERO_END; i += 32768) ws[i] = 0.f;

    int code = t >> 5;
    int q = t & 31;
    float4 v = ((const float4*)(emb + (size_t)code * D_DIM))[q];
    int chunk = code >> 6, c = code & 63;
    size_t hbase = (size_t)chunk * CH64_U + (size_t)c * EPAD + q * 4;
    size_t lbase = hbase + CH_LO;
    float vv[4] = {v.x, v.y, v.z, v.w};
    ushort4 hi, lo;
    unsigned short* hp = (unsigned short*)&hi;
    unsigned short* lp = (unsigned short*)&lo;
#pragma unroll
    for (int i = 0; i < 4; ++i) {
        unsigned short hb = f2h_bits(vv[i]);
        hp[i] = hb;
        lp[i] = f2h_bits(vv[i] - h_bits2f(hb));
    }
    *(ushort4*)(eimg + hbase) = hi;
    *(ushort4*)(eimg + lbase) = lo;

    float s = v.x * v.x + v.y * v.y + v.z * v.z + v.w * v.w;
#pragma unroll
    for (int o = 1; o < 32; o <<= 1) s += __shfl_xor(s, o, 64);
    if (q == 0) enorm[code] = s;
}

// ---------------------------------------------------------------------------
__device__ inline void top2_update(float s, int code, float& s1, int& i1, float& s2, int& i2) {
    bool b1 = s < s1;
    bool b2 = s < s2;
    s2 = b1 ? s1 : (b2 ? s : s2);
    i2 = b1 ? i1 : (b2 ? code : i2);
    s1 = b1 ? s : s1;
    i1 = b1 ? code : i1;
}

__device__ inline void top2_merge(float& s1, int& i1, float& s2, int& i2,
                                  float t1, int j1, float t2, int j2) {
    bool bf = (t1 < s1) || (t1 == s1 && j1 < i1);
    float ns1 = bf ? t1 : s1;  int ni1 = bf ? j1 : i1;
    float ca  = bf ? s1 : t1;  int ia  = bf ? i1 : j1;
    float cb  = bf ? t2 : s2;  int ib  = bf ? j2 : i2;
    bool bs = (ca < cb) || (ca == cb && ia < ib);
    s1 = ns1; i1 = ni1;
    s2 = bs ? ca : cb; i2 = bs ? ia : ib;
}

// ---------------------------------------------------------------------------
// Score (quarter-split): block = (row_group, quarter). 256 thr = 4 waves,
// NT=2 -> 128 rows x 256 codes per block. Grid 2048 -> 8192 waves.
// LDS: 64-code chunk (34816 B) + en (1 KB) -> 4 blocks/CU -> 16 waves/CU.
// Emits top-2 (s,i) per (row, quarter); quarter 0 also writes znorm.
// ---------------------------------------------------------------------------
__global__ __launch_bounds__(256, 4) void vq_score(
    const float* __restrict__ z, const unsigned short* __restrict__ eimg,
    const float* __restrict__ enorm_g, uint4* __restrict__ cand,
    float* __restrict__ znorm)
{
    __shared__ __align__(16) unsigned short lds[CH64_U];   // 34816 B
    __shared__ __align__(16) float lds_en[QCODES];         // 1 KB

    const int tid  = threadIdx.x;
    const int wv   = tid >> 6;
    const int lane = tid & 63;
    const int l16  = lane & 15;
    const int quad = lane >> 4;
    const int qs   = blockIdx.x & 3;
    const int rg   = blockIdx.x >> 2;
    const int rowbase = rg * 128 + wv * 32;

    if (tid < QCODES / 4)
        ((float4*)lds_en)[tid] = ((const float4*)(enorm_g + qs * QCODES))[tid];

    // stage chunk 0 of this quarter (per wave: 8704 B)
    {
        const char* gs = (const char*)(eimg + (size_t)(qs * 4) * CH64_U);
        char* ls = (char*)lds;
        int wb = wv * 8704;
#pragma unroll
        for (int i = 0; i < 8; ++i)
            gld16(gs + wb + i * 1024 + lane * 16, ls + wb + i * 1024);
        if (lane < 32) gld16(gs + wb + 8192 + lane * 16, ls + wb + 8192);
    }

    // resident z fragments (fp16 hi/lo) + znorm
    h8_t zh[NT][4], zl[NT][4];
#pragma unroll
    for (int nt = 0; nt < NT; ++nt) {
        int row = rowbase + nt * 16 + l16;
        const float* zr = z + (size_t)row * D_DIM;
        float zn = 0.f;
#pragma unroll
        for (int ks = 0; ks < 4; ++ks) {
            const float4* p = (const float4*)(zr + ks * 32 + quad * 8);
            float4 a = p[0], b = p[1];
            float v[8] = {a.x, a.y, a.z, a.w, b.x, b.y, b.z, b.w};
#pragma unroll
            for (int i = 0; i < 8; ++i) {
                _Float16 hh = (_Float16)v[i];
                zh[nt][ks][i] = hh;
                zl[nt][ks][i] = (_Float16)(v[i] - (float)hh);
                zn += v[i] * v[i];
            }
        }
        zn += __shfl_xor(zn, 16, 64);
        zn += __shfl_xor(zn, 32, 64);
        if (qs == 0 && quad == 0) znorm[row] = zn;
    }

    float s1[NT], s2[NT];
    int   i1[NT], i2[NT];
#pragma unroll
    for (int nt = 0; nt < NT; ++nt) { s1[nt] = 3.4e38f; s2[nt] = 3.4e38f; i1[nt] = 0; i2[nt] = 0; }

    __syncthreads();   // staging + en drained

    for (int ch = 0; ch < 4; ++ch) {
#pragma unroll
        for (int cg = 0; cg < 2; ++cg) {     // 32 codes per pass
            f4_t acc[2][NT];
#pragma unroll
            for (int ct = 0; ct < 2; ++ct)
#pragma unroll
                for (int nt = 0; nt < NT; ++nt) acc[ct][nt] = (f4_t)(0.f);

#pragma unroll
            for (int ks = 0; ks < 4; ++ks) {
                h8_t ah[2], al[2];
#pragma unroll
                for (int ct = 0; ct < 2; ++ct) {
                    int cl = cg * 32 + ct * 16 + l16;
                    int base = cl * EPAD + ks * 32 + quad * 8;
                    ah[ct] = *(const h8_t*)&lds[base];
                    al[ct] = *(const h8_t*)&lds[CH_LO + base];
                }
#pragma unroll
                for (int ct = 0; ct < 2; ++ct)
#pragma unroll
                    for (int nt = 0; nt < NT; ++nt) {
                        acc[ct][nt] = __builtin_amdgcn_mfma_f32_16x16x32_f16(
                            ah[ct], zh[nt][ks], acc[ct][nt], 0, 0, 0);
                        acc[ct][nt] = __builtin_amdgcn_mfma_f32_16x16x32_f16(
                            al[ct], zh[nt][ks], acc[ct][nt], 0, 0, 0);
                        acc[ct][nt] = __builtin_amdgcn_mfma_f32_16x16x32_f16(
                            ah[ct], zl[nt][ks], acc[ct][nt], 0, 0, 0);
                    }
            }

            // selection: within-lane 8-way tournament, then one top2_update
            int lcb = ch * 64 + cg * 32;
            float4 e0 = *(const float4*)&lds_en[lcb + quad * 4];
            float4 e1 = *(const float4*)&lds_en[lcb + 16 + quad * 4];
            float env0[4] = {e0.x, e0.y, e0.z, e0.w};
            float env1[4] = {e1.x, e1.y, e1.z, e1.w};
            int cb = qs * QCODES + lcb + quad * 4;
#pragma unroll
            for (int nt = 0; nt < NT; ++nt) {
                float sv[8];
#pragma unroll
                for (int r = 0; r < 4; ++r) {
                    sv[r]     = fmaf(-2.f, acc[0][nt][r], env0[r]);
                    sv[4 + r] = fmaf(-2.f, acc[1][nt][r], env1[r]);
                }
                float bs_ = sv[0]; int li = 0;
#pragma unroll
                for (int k = 1; k < 8; ++k) {
                    bool t = sv[k] < bs_;
                    bs_ = t ? sv[k] : bs_;
                    li  = t ? k : li;
                }
                int code = cb + ((li >> 2) << 4) + (li & 3);
                top2_update(bs_, code, s1[nt], i1[nt], s2[nt], i2[nt]);
            }
        }
        __syncthreads();   // all waves done reading this chunk
        if (ch + 1 < 4) {
            const char* gs = (const char*)(eimg + (size_t)(qs * 4 + ch + 1) * CH64_U);
            char* ls = (char*)lds;
            int wb = wv * 8704;
#pragma unroll
            for (int i = 0; i < 8; ++i)
                gld16(gs + wb + i * 1024 + lane * 16, ls + wb + i * 1024);
            if (lane < 32) gld16(gs + wb + 8192 + lane * 16, ls + wb + 8192);
            __syncthreads();   // staging drained
        }
    }

    // cross-quad merge (quads saw disjoint codes)
#pragma unroll
    for (int off = 16; off <= 32; off <<= 1) {
#pragma unroll
        for (int nt = 0; nt < NT; ++nt) {
            float t1 = __shfl_xor(s1[nt], off, 64);
            int   j1 = __shfl_xor(i1[nt], off, 64);
            float t2 = __shfl_xor(s2[nt], off, 64);
            int   j2 = __shfl_xor(i2[nt], off, 64);
            top2_merge(s1[nt], i1[nt], s2[nt], i2[nt], t1, j1, t2, j2);
        }
    }

    if (lane < 16) {
#pragma unroll
        for (int nt = 0; nt < NT; ++nt) {
            int row = rowbase + nt * 16 + l16;
            uint4 p = {__float_as_uint(s1[nt]), (unsigned int)i1[nt],
                       __float_as_uint(s2[nt]), (unsigned int)i2[nt]};
            cand[(size_t)row * 4 + qs] = p;
        }
    }
}

// ---------------------------------------------------------------------------
// Finish: merge 4 quarters' top-2, rare exact-fp32 rescue, outputs
// idx/fidx/cnt/loss. 1 thread per row; grid 256 x 256.
// ---------------------------------------------------------------------------
__global__ __launch_bounds__(256) void vq_finish(
    const float* __restrict__ z, const float* __restrict__ emb,
    const float* __restrict__ enorm, const uint4* __restrict__ cand,
    const float* __restrict__ znorm,
    float* __restrict__ out_idx, unsigned int* __restrict__ fidx,
    int* __restrict__ cnt, float* __restrict__ loss_acc)
{
    int row = blockIdx.x * 256 + threadIdx.x;
    uint4 q0 = cand[(size_t)row * 4 + 0];
    uint4 q1 = cand[(size_t)row * 4 + 1];
    uint4 q2 = cand[(size_t)row * 4 + 2];
    uint4 q3 = cand[(size_t)row * 4 + 3];

    float s1 = __uint_as_float(q0.x); int i1 = (int)q0.y;
    float s2 = __uint_as_float(q0.z); int i2 = (int)q0.w;
    top2_merge(s1, i1, s2, i2, __uint_as_float(q1.x), (int)q1.y,
                               __uint_as_float(q1.z), (int)q1.w);
    top2_merge(s1, i1, s2, i2, __uint_as_float(q2.x), (int)q2.y,
                               __uint_as_float(q2.z), (int)q2.w);
    top2_merge(s1, i1, s2, i2, __uint_as_float(q3.x), (int)q3.y,
                               __uint_as_float(q3.z), (int)q3.w);

    int best = i1;
    float sbest = s1;
    if (s2 - s1 < RESCUE_EPS) {   // rare: exact fp32 rescore of all 8
        int cs8[8] = {(int)q0.y, (int)q0.w, (int)q1.y, (int)q1.w,
                      (int)q2.y, (int)q2.w, (int)q3.y, (int)q3.w};
        const float4* zr = (const float4*)(z + (size_t)row * D_DIM);
        float bs = 3.4e38f; int bi = 0x7fffffff;
        for (int c = 0; c < 8; ++c) {
            int j = cs8[c];
            const float4* ep = (const float4*)(emb + (size_t)j * D_DIM);
            float p = 0.f;
            for (int i = 0; i < 32; ++i) {
                float4 a = ep[i], zv = zr[i];
                p += zv.x * a.x + zv.y * a.y + zv.z * a.z + zv.w * a.w;
            }
            float s = enorm[j] - 2.f * p;
            if (s < bs || (s == bs && j < bi)) { bs = s; bi = j; }
        }
        best = bi; sbest = bs;
    }

    out_idx[row] = (float)best;
    fidx[row] = (unsigned int)best;
    atomicAdd(cnt + best, 1);

    float ls = sbest + znorm[row];   // ||e_best - z||^2 via identity
#pragma unroll
    for (int off = 32; off > 0; off >>= 1) ls += __shfl_down(ls, off, 64);
    if ((threadIdx.x & 63) == 0) atomicAdd(loss_acc, ls);
}

// ---------------------------------------------------------------------------
// z_q copy: out_zq[row] = emb[best[row]] (== z + (z_q - z) to ~1 ulp).
// 32 threads/row, coalesced 512 B bursts. Grid 8192 x 256.
// ---------------------------------------------------------------------------
__global__ __launch_bounds__(256) void vq_zqcopy(
    const float* __restrict__ emb, const unsigned int* __restrict__ fidx,
    float* __restrict__ out_zq)
{
    int t = blockIdx.x * 256 + threadIdx.x;
    int row = t >> 5, off = t & 31;
    int best = (int)fidx[row];
    ((float4*)out_zq)[(size_t)row * 32 + off] =
        ((const float4*)emb)[(size_t)best * 32 + off];
}

// ---------------------------------------------------------------------------
// Mid: scan cnt -> cursor, ncs/smoothed/loss outputs. 1 block, 1024 thr.
// ---------------------------------------------------------------------------
__global__ void vq_mid(const float* __restrict__ cs, const int* __restrict__ cnt,
                       const float* __restrict__ loss_acc,
                       float* __restrict__ out_ncs, float* __restrict__ out_loss,
                       float* __restrict__ smoothed, int* __restrict__ cursor)
{
    __shared__ int tmp[K_CODES];
    __shared__ float red[K_CODES];
    int k = threadIdx.x;
    int c = cnt[k];
    tmp[k] = c;
    float ncs = cs[k] * DECAY_F + OMD_F * (float)c;
    out_ncs[k] = ncs;
    red[k] = ncs;
    __syncthreads();
    for (int off = 1; off < K_CODES; off <<= 1) {
        int t = (k >= off) ? tmp[k - off] : 0;
        __syncthreads();
        tmp[k] += t;
        __syncthreads();
    }
    cursor[k] = tmp[k] - c;
    for (int s = 512; s > 0; s >>= 1) {
        if (k < s) red[k] += red[k + s];
        __syncthreads();
    }
    float n = red[0];
    smoothed[k] = (ncs + EPS_F) / (n + (float)K_CODES * EPS_F) * n;
    if (k == 0) out_loss[0] = loss_acc[0] / (float)((size_t)N_ROWS * D_DIM);
}

__global__ void vq_scatter(const unsigned int* __restrict__ fidx,
                           int* __restrict__ cursor, unsigned int* __restrict__ bucket,
                           int* __restrict__ scode)
{
    int row = blockIdx.x * blockDim.x + threadIdx.x;
    int k = (int)fidx[row];
    int slot = atomicAdd(cursor + k, 1);
    bucket[slot] = (unsigned int)row;
    scode[slot]  = k;
}

// ---------------------------------------------------------------------------
// Skew-oblivious segment sum over code-sorted slots (R4-proven).
// ---------------------------------------------------------------------------
__global__ __launch_bounds__(128) void vq_segsum(
    const float* __restrict__ z, const unsigned int* __restrict__ bucket,
    const int* __restrict__ scode, float* __restrict__ be)
{
    __shared__ int sb[SEG_TILE];
    __shared__ int sc[SEG_TILE];
    const int tid = threadIdx.x;
    const int t0  = blockIdx.x * SEG_TILE;

    if (tid < SEG_TILE) sb[tid] = (int)bucket[t0 + tid];
    else if (tid < 2 * SEG_TILE) sc[tid - SEG_TILE] = scode[t0 + tid - SEG_TILE];
    __syncthreads();

    const int d = tid;
    float acc = 0.f;
    int cur = sc[0];

    for (int i = 0; i < SEG_TILE; i += 8) {
        float v[8];
#pragma unroll
        for (int jx = 0; jx < 8; ++jx)
            v[jx] = z[(size_t)sb[i + jx] * D_DIM + d];
#pragma unroll
        for (int jx = 0; jx < 8; ++jx) {
            int c = sc[i + jx];
            if (c != cur) {
                atomicAdd(be + (size_t)cur * D_DIM + d, acc);
                acc = 0.f;
                cur = c;
            }
            acc += v[jx];
        }
    }
    atomicAdd(be + (size_t)cur * D_DIM + d, acc);
}

__global__ void vq_fin2(const float* __restrict__ ema_w, const float* __restrict__ be,
                        const float* __restrict__ smoothed,
                        float* __restrict__ out_emb, float* __restrict__ out_ema)
{
    int i = blockIdx.x * blockDim.x + threadIdx.x;
    float e = ema_w[i] * DECAY_F + OMD_F * be[i];
    out_ema[i] = e;
    out_emb[i] = e / smoothed[i >> 7];
}

// ---------------------------------------------------------------------------
extern "C" void kernel_launch(void* const* d_in, const int* in_sizes, int n_in,
                              void* d_out, int out_size, void* d_ws, size_t ws_size,
                              hipStream_t stream) {
    const float* z   = (const float*)d_in[0];
    const float* emb = (const float*)d_in[1];
    const float* cs  = (const float*)d_in[2];
    const float* ema = (const float*)d_in[3];

    float* out    = (float*)d_out;
    float* o_zq   = out;
    float* o_idx  = o_zq + (size_t)N_ROWS * D_DIM;
    float* o_loss = o_idx + N_ROWS;
    float* o_emb  = o_loss + 1;
    float* o_ncs  = o_emb + K_CODES * D_DIM;
    float* o_ema  = o_ncs + K_CODES;

    float* ws = (float*)d_ws;
    int*            cnt      = (int*)(ws + WS_CNT);
    float*          lacc     = ws + WS_LOSS;
    float*          be       = ws + WS_BE;
    float*          enorm    = ws + WS_ENORM;
    float*          smoothed = ws + WS_SMOOTH;
    int*            cursor   = (int*)(ws + WS_CUR);
    unsigned int*   fidx     = (unsigned int*)(ws + WS_FIDX);
    float*          znorm    = ws + WS_ZNORM;
    uint4*          cand     = (uint4*)(ws + WS_CAND);
    unsigned int*   bucket   = (unsigned int*)(ws + WS_BUCKET);
    int*            scode    = (int*)(ws + WS_SCODE);
    unsigned short* eimg     = (unsigned short*)(ws + WS_EIMG);

    vq_prep<<<128, 256, 0, stream>>>(emb, ws, enorm, eimg);
    vq_score<<<2048, 256, 0, stream>>>(z, eimg, enorm, cand, znorm);
    vq_finish<<<256, 256, 0, stream>>>(z, emb, enorm, cand, znorm,
                                       o_idx, fidx, cnt, lacc);
    vq_zqcopy<<<8192, 256, 0, stream>>>(emb, fidx, o_zq);
    vq_mid<<<1, K_CODES, 0, stream>>>(cs, cnt, lacc, o_ncs, o_loss, smoothed, cursor);
    vq_scatter<<<N_ROWS / 256, 256, 0, stream>>>(fidx, cursor, bucket, scode);
    vq_segsum<<<N_ROWS / SEG_TILE, 128, 0, stream>>>(z, bucket, scode, be);
    vq_fin2<<<K_CODES * D_DIM / 256, 256, 0, stream>>>(ema, be, smoothed, o_emb, o_ema);
}

// Round 8
// 249.750 us; speedup vs baseline: 1.1920x; 1.1920x over previous
//
#include <hip/hip_runtime.h>

#define K_CODES 1024
#define D_DIM 128
#define N_ROWS 65536
#define DECAY_F 0.99f
#define OMD_F 0.01f
#define EPS_F 1e-5f

#define EPAD 136                        // padded fp16 row (272 B)
#define CHUNK_CODES 128
#define CHUNK_USHORT (2 * CHUNK_CODES * EPAD)   // 34816 ushorts = 69632 B
#define CH_LO (CHUNK_CODES * EPAD)      // 17408 ushorts: lo image offset
#define NT 4                            // row tiles per wave (64 rows/wave)
#define HALF_CODES 512
#define HALF_CHUNKS 4
#define SEG_TILE 64
#define RESCUE_EPS 1e-3f

// ---------------------------------------------------------------------------
// ws layout (float units). [0, WS_ZERO_END) zeroed by vq_prep every call.
//   cnt[1024] | loss[1] | rcount[1] | pad[2] | be[131072] || enorm[1024] |
//   smoothed[1024] | cursor[1024] | fidx[65536] | znorm[65536] |
//   rlist[65536] | cand uint4[65536][2] | bucket[65536] | scode[65536] |
//   eimg ushort[8][2][128][136]
// ---------------------------------------------------------------------------
#define WS_CNT     0
#define WS_LOSS    1024
#define WS_RC      1025
#define WS_BE      1028
#define WS_ZERO_END (1028 + 131072)     // 132100
#define WS_ENORM   132100
#define WS_SMOOTH  133124
#define WS_CUR     134148
#define WS_FIDX    135172
#define WS_ZNORM   200708
#define WS_RLIST   266244
#define WS_CAND    331780               // 524288 floats (uint4[131072])
#define WS_BUCKET  856068
#define WS_SCODE   921604
#define WS_EIMG    987140               // byte off 3948560 (16B aligned)

typedef _Float16 h8_t __attribute__((ext_vector_type(8)));
typedef float    f4_t __attribute__((ext_vector_type(4)));

__device__ inline unsigned short f2h_bits(float f) {
    _Float16 h = (_Float16)f;
    return __builtin_bit_cast(unsigned short, h);
}
__device__ inline float h_bits2f(unsigned short u) {
    _Float16 h = __builtin_bit_cast(_Float16, u);
    return (float)h;
}

// async global->LDS, 16 B/lane (HW: lds dest = uniform base + lane*16)
__device__ inline void gld16(const void* g, void* l) {
    __builtin_amdgcn_global_load_lds(
        (const __attribute__((address_space(1))) void*)g,
        (__attribute__((address_space(3))) void*)l, 16, 0, 0);
}

// ---------------------------------------------------------------------------
// Prep: zero cnt/loss/rcount/be + enorm + fp16 hi/lo split image.
// grid 128 x 256.
// ---------------------------------------------------------------------------
__global__ void vq_prep(const float* __restrict__ emb, float* __restrict__ ws,
                        float* __restrict__ enorm, unsigned short* __restrict__ eimg) {
    int t = blockIdx.x * blockDim.x + threadIdx.x;   // 32768
    for (int i = t; i < WS_ZERO_END; i += 32768) ws[i] = 0.f;

    int code = t >> 5;
    int q = t & 31;
    float4 v = ((const float4*)(emb + (size_t)code * D_DIM))[q];
    int chunk = code >> 7, c = code & 127;
    size_t hbase = (size_t)chunk * CHUNK_USHORT + (size_t)c * EPAD + q * 4;
    size_t lbase = hbase + CH_LO;
    float vv[4] = {v.x, v.y, v.z, v.w};
    ushort4 hi, lo;
    unsigned short* hp = (unsigned short*)&hi;
    unsigned short* lp = (unsigned short*)&lo;
#pragma unroll
    for (int i = 0; i < 4; ++i) {
        unsigned short hb = f2h_bits(vv[i]);
        hp[i] = hb;
        lp[i] = f2h_bits(vv[i] - h_bits2f(hb));
    }
    *(ushort4*)(eimg + hbase) = hi;
    *(ushort4*)(eimg + lbase) = lo;

    float s = v.x * v.x + v.y * v.y + v.z * v.z + v.w * v.w;
#pragma unroll
    for (int o = 1; o < 32; o <<= 1) s += __shfl_xor(s, o, 64);
    if (q == 0) enorm[code] = s;
}

// ---------------------------------------------------------------------------
__device__ inline void top2_update(float s, int code, float& s1, int& i1, float& s2, int& i2) {
    bool b1 = s < s1;
    bool b2 = s < s2;
    s2 = b1 ? s1 : (b2 ? s : s2);
    i2 = b1 ? i1 : (b2 ? code : i2);
    s1 = b1 ? s : s1;
    i1 = b1 ? code : i1;
}

__device__ inline void top2_merge(float& s1, int& i1, float& s2, int& i2,
                                  float t1, int j1, float t2, int j2) {
    bool bf = (t1 < s1) || (t1 == s1 && j1 < i1);
    float ns1 = bf ? t1 : s1;  int ni1 = bf ? j1 : i1;
    float ca  = bf ? s1 : t1;  int ia  = bf ? i1 : j1;
    float cb  = bf ? t2 : s2;  int ib  = bf ? j2 : i2;
    bool bs = (ca < cb) || (ca == cb && ia < ib);
    s1 = ns1; i1 = ni1;
    s2 = bs ? ca : cb; i2 = bs ? ia : ib;
}

// ---------------------------------------------------------------------------
// Score (half-split, R6 structure, fp16 3-term): block = (row_group, half).
// 256 thr = 4 waves, NT=4 -> 256 rows x 512 codes. Grid 512 -> 8 waves/CU.
// LDS 69632+2048 B -> 2 blocks/CU. Emits (s,i) top-2 per (row, half);
// half 0 also writes znorm.
// ---------------------------------------------------------------------------
__global__ __launch_bounds__(256, 2) void vq_score(
    const float* __restrict__ z, const unsigned short* __restrict__ eimg,
    const float* __restrict__ enorm_g, uint4* __restrict__ cand,
    float* __restrict__ znorm)
{
    __shared__ __align__(16) unsigned short lds[CHUNK_USHORT];   // 69632 B
    __shared__ __align__(16) float lds_en[HALF_CODES];           // 2 KB

    const int tid  = threadIdx.x;
    const int wv   = tid >> 6;
    const int lane = tid & 63;
    const int l16  = lane & 15;
    const int quad = lane >> 4;
    const int half = blockIdx.x & 1;
    const int rg   = blockIdx.x >> 1;
    const int rowbase = rg * 256 + wv * 64;

    if (tid < HALF_CODES / 4)
        ((float4*)lds_en)[tid] = ((const float4*)(enorm_g + half * HALF_CODES))[tid];

    // stage chunk 0 of this half (per wave: 17408 B = 17 x 1 KB)
    {
        const char* gs = (const char*)(eimg + (size_t)(half * HALF_CHUNKS) * CHUNK_USHORT);
        char* ls = (char*)lds;
        int wb = wv * 17408;
#pragma unroll
        for (int i = 0; i < 17; ++i)
            gld16(gs + wb + i * 1024 + lane * 16, ls + wb + i * 1024);
    }

    // resident z fragments (fp16 hi/lo) + znorm
    h8_t zh[NT][4], zl[NT][4];
#pragma unroll
    for (int nt = 0; nt < NT; ++nt) {
        int row = rowbase + nt * 16 + l16;
        const float* zr = z + (size_t)row * D_DIM;
        float zn = 0.f;
#pragma unroll
        for (int ks = 0; ks < 4; ++ks) {
            const float4* p = (const float4*)(zr + ks * 32 + quad * 8);
            float4 a = p[0], b = p[1];
            float v[8] = {a.x, a.y, a.z, a.w, b.x, b.y, b.z, b.w};
#pragma unroll
            for (int i = 0; i < 8; ++i) {
                _Float16 hh = (_Float16)v[i];
                zh[nt][ks][i] = hh;
                zl[nt][ks][i] = (_Float16)(v[i] - (float)hh);
                zn += v[i] * v[i];
            }
        }
        zn += __shfl_xor(zn, 16, 64);
        zn += __shfl_xor(zn, 32, 64);
        if (half == 0 && quad == 0) znorm[row] = zn;
    }

    float s1[NT], s2[NT];
    int   i1[NT], i2[NT];
#pragma unroll
    for (int nt = 0; nt < NT; ++nt) { s1[nt] = 3.4e38f; s2[nt] = 3.4e38f; i1[nt] = 0; i2[nt] = 0; }

    __syncthreads();   // staging + en drained

    for (int c = 0; c < HALF_CHUNKS; ++c) {
#pragma unroll
        for (int cg = 0; cg < 4; ++cg) {     // 32 codes per pass
            f4_t acc[2][NT];
#pragma unroll
            for (int ct = 0; ct < 2; ++ct)
#pragma unroll
                for (int nt = 0; nt < NT; ++nt) acc[ct][nt] = (f4_t)(0.f);

#pragma unroll
            for (int ks = 0; ks < 4; ++ks) {
                h8_t ah[2], al[2];
#pragma unroll
                for (int ct = 0; ct < 2; ++ct) {
                    int cl = cg * 32 + ct * 16 + l16;
                    int base = cl * EPAD + ks * 32 + quad * 8;
                    ah[ct] = *(const h8_t*)&lds[base];
                    al[ct] = *(const h8_t*)&lds[CH_LO + base];
                }
#pragma unroll
                for (int ct = 0; ct < 2; ++ct)
#pragma unroll
                    for (int nt = 0; nt < NT; ++nt) {
                        acc[ct][nt] = __builtin_amdgcn_mfma_f32_16x16x32_f16(
                            ah[ct], zh[nt][ks], acc[ct][nt], 0, 0, 0);
                        acc[ct][nt] = __builtin_amdgcn_mfma_f32_16x16x32_f16(
                            al[ct], zh[nt][ks], acc[ct][nt], 0, 0, 0);
                        acc[ct][nt] = __builtin_amdgcn_mfma_f32_16x16x32_f16(
                            ah[ct], zl[nt][ks], acc[ct][nt], 0, 0, 0);
                    }
            }

#pragma unroll
            for (int ct = 0; ct < 2; ++ct) {
                int lc = c * 128 + cg * 32 + ct * 16 + quad * 4;
                float4 en4 = *(const float4*)&lds_en[lc];
                float env[4] = {en4.x, en4.y, en4.z, en4.w};
                int gc = half * HALF_CODES + lc;
#pragma unroll
                for (int nt = 0; nt < NT; ++nt)
#pragma unroll
                    for (int r = 0; r < 4; ++r) {
                        float s = fmaf(-2.f, acc[ct][nt][r], env[r]);
                        top2_update(s, gc + r, s1[nt], i1[nt], s2[nt], i2[nt]);
                    }
            }
        }
        __syncthreads();   // all waves done reading this chunk
        if (c + 1 < HALF_CHUNKS) {
            const char* gs = (const char*)(eimg +
                (size_t)(half * HALF_CHUNKS + c + 1) * CHUNK_USHORT);
            char* ls = (char*)lds;
            int wb = wv * 17408;
#pragma unroll
            for (int i = 0; i < 17; ++i)
                gld16(gs + wb + i * 1024 + lane * 16, ls + wb + i * 1024);
            __syncthreads();   // staging drained
        }
    }

    // cross-quad merge (quads saw disjoint codes)
#pragma unroll
    for (int off = 16; off <= 32; off <<= 1) {
#pragma unroll
        for (int nt = 0; nt < NT; ++nt) {
            float t1 = __shfl_xor(s1[nt], off, 64);
            int   j1 = __shfl_xor(i1[nt], off, 64);
            float t2 = __shfl_xor(s2[nt], off, 64);
            int   j2 = __shfl_xor(i2[nt], off, 64);
            top2_merge(s1[nt], i1[nt], s2[nt], i2[nt], t1, j1, t2, j2);
        }
    }

    if (lane < 16) {
#pragma unroll
        for (int nt = 0; nt < NT; ++nt) {
            int row = rowbase + nt * 16 + l16;
            uint4 p = {__float_as_uint(s1[nt]), (unsigned int)i1[nt],
                       __float_as_uint(s2[nt]), (unsigned int)i2[nt]};
            cand[(size_t)row * 2 + half] = p;
        }
    }
}

// ---------------------------------------------------------------------------
// Finish: merge 2 halves' top-2; commit when gap safe, else defer to rescue
// list (no divergent slow path here). 1 thread per row; grid 256 x 256.
// ---------------------------------------------------------------------------
__global__ __launch_bounds__(256) void vq_finish(
    const uint4* __restrict__ cand, const float* __restrict__ znorm,
    float* __restrict__ out_idx, unsigned int* __restrict__ fidx,
    int* __restrict__ cnt, float* __restrict__ loss_acc,
    int* __restrict__ rcount, unsigned int* __restrict__ rlist)
{
    int row = blockIdx.x * 256 + threadIdx.x;
    uint4 q0 = cand[(size_t)row * 2 + 0];
    uint4 q1 = cand[(size_t)row * 2 + 1];

    float s1 = __uint_as_float(q0.x); int i1 = (int)q0.y;
    float s2 = __uint_as_float(q0.z); int i2 = (int)q0.w;
    top2_merge(s1, i1, s2, i2, __uint_as_float(q1.x), (int)q1.y,
                               __uint_as_float(q1.z), (int)q1.w);

    float ls = 0.f;
    if (s2 - s1 >= RESCUE_EPS) {
        out_idx[row] = (float)i1;
        fidx[row] = (unsigned int)i1;
        atomicAdd(cnt + i1, 1);
        ls = s1 + znorm[row];            // ||e_best - z||^2 via identity
    } else {
        int slot = atomicAdd(rcount, 1); // rare: exact rescore later
        rlist[slot] = (unsigned int)row;
    }

#pragma unroll
    for (int off = 32; off > 0; off >>= 1) ls += __shfl_down(ls, off, 64);
    if ((threadIdx.x & 63) == 0) atomicAdd(loss_acc, ls);
}

// ---------------------------------------------------------------------------
// Rescue: exact fp32 rescore of the 4 candidates for deferred rows.
// Fixed grid 32 x 256, grid-stride over the list (usually empty).
// ---------------------------------------------------------------------------
__global__ __launch_bounds__(256) void vq_rescue(
    const float* __restrict__ z, const float* __restrict__ emb,
    const float* __restrict__ enorm, const uint4* __restrict__ cand,
    const float* __restrict__ znorm, const int* __restrict__ rcount,
    const unsigned int* __restrict__ rlist,
    float* __restrict__ out_idx, unsigned int* __restrict__ fidx,
    int* __restrict__ cnt, float* __restrict__ loss_acc)
{
    int n = *rcount;
    for (int i = blockIdx.x * 256 + threadIdx.x; i < n; i += 32 * 256) {
        int row = (int)rlist[i];
        uint4 q0 = cand[(size_t)row * 2 + 0];
        uint4 q1 = cand[(size_t)row * 2 + 1];
        int cs4[4] = {(int)q0.y, (int)q0.w, (int)q1.y, (int)q1.w};
        const float4* zr = (const float4*)(z + (size_t)row * D_DIM);
        float bs = 3.4e38f; int bi = 0x7fffffff;
        for (int c = 0; c < 4; ++c) {
            int j = cs4[c];
            const float4* ep = (const float4*)(emb + (size_t)j * D_DIM);
            float p = 0.f;
            for (int k = 0; k < 32; ++k) {
                float4 a = ep[k], zv = zr[k];
                p += zv.x * a.x + zv.y * a.y + zv.z * a.z + zv.w * a.w;
            }
            float s = enorm[j] - 2.f * p;
            if (s < bs || (s == bs && j < bi)) { bs = s; bi = j; }
        }
        out_idx[row] = (float)bi;
        fidx[row] = (unsigned int)bi;
        atomicAdd(cnt + bi, 1);
        atomicAdd(loss_acc, bs + znorm[row]);
    }
}

// ---------------------------------------------------------------------------
// z_q copy: out_zq[row] = emb[best[row]]. 32 thr/row, 512 B bursts.
// ---------------------------------------------------------------------------
__global__ __launch_bounds__(256) void vq_zqcopy(
    const float* __restrict__ emb, const unsigned int* __restrict__ fidx,
    float* __restrict__ out_zq)
{
    int t = blockIdx.x * 256 + threadIdx.x;
    int row = t >> 5, off = t & 31;
    int best = (int)fidx[row];
    ((float4*)out_zq)[(size_t)row * 32 + off] =
        ((const float4*)emb)[(size_t)best * 32 + off];
}

// ---------------------------------------------------------------------------
// Mid: scan cnt -> cursor, ncs/smoothed/loss outputs. 1 block, 1024 thr.
// ---------------------------------------------------------------------------
__global__ void vq_mid(const float* __restrict__ cs, const int* __restrict__ cnt,
                       const float* __restrict__ loss_acc,
                       float* __restrict__ out_ncs, float* __restrict__ out_loss,
                       float* __restrict__ smoothed, int* __restrict__ cursor)
{
    __shared__ int tmp[K_CODES];
    __shared__ float red[K_CODES];
    int k = threadIdx.x;
    int c = cnt[k];
    tmp[k] = c;
    float ncs = cs[k] * DECAY_F + OMD_F * (float)c;
    out_ncs[k] = ncs;
    red[k] = ncs;
    __syncthreads();
    for (int off = 1; off < K_CODES; off <<= 1) {
        int t = (k >= off) ? tmp[k - off] : 0;
        __syncthreads();
        tmp[k] += t;
        __syncthreads();
    }
    cursor[k] = tmp[k] - c;
    for (int s = 512; s > 0; s >>= 1) {
        if (k < s) red[k] += red[k + s];
        __syncthreads();
    }
    float n = red[0];
    smoothed[k] = (ncs + EPS_F) / (n + (float)K_CODES * EPS_F) * n;
    if (k == 0) out_loss[0] = loss_acc[0] / (float)((size_t)N_ROWS * D_DIM);
}

__global__ void vq_scatter(const unsigned int* __restrict__ fidx,
                           int* __restrict__ cursor, unsigned int* __restrict__ bucket,
                           int* __restrict__ scode)
{
    int row = blockIdx.x * blockDim.x + threadIdx.x;
    int k = (int)fidx[row];
    int slot = atomicAdd(cursor + k, 1);
    bucket[slot] = (unsigned int)row;
    scode[slot]  = k;
}

// ---------------------------------------------------------------------------
// Skew-oblivious segment sum over code-sorted slots (R4-proven).
// ---------------------------------------------------------------------------
__global__ __launch_bounds__(128) void vq_segsum(
    const float* __restrict__ z, const unsigned int* __restrict__ bucket,
    const int* __restrict__ scode, float* __restrict__ be)
{
    __shared__ int sb[SEG_TILE];
    __shared__ int sc[SEG_TILE];
    const int tid = threadIdx.x;
    const int t0  = blockIdx.x * SEG_TILE;

    if (tid < SEG_TILE) sb[tid] = (int)bucket[t0 + tid];
    else if (tid < 2 * SEG_TILE) sc[tid - SEG_TILE] = scode[t0 + tid - SEG_TILE];
    __syncthreads();

    const int d = tid;
    float acc = 0.f;
    int cur = sc[0];

    for (int i = 0; i < SEG_TILE; i += 8) {
        float v[8];
#pragma unroll
        for (int jx = 0; jx < 8; ++jx)
            v[jx] = z[(size_t)sb[i + jx] * D_DIM + d];
#pragma unroll
        for (int jx = 0; jx < 8; ++jx) {
            int c = sc[i + jx];
            if (c != cur) {
                atomicAdd(be + (size_t)cur * D_DIM + d, acc);
                acc = 0.f;
                cur = c;
            }
            acc += v[jx];
        }
    }
    atomicAdd(be + (size_t)cur * D_DIM + d, acc);
}

__global__ void vq_fin2(const float* __restrict__ ema_w, const float* __restrict__ be,
                        const float* __restrict__ smoothed,
                        float* __restrict__ out_emb, float* __restrict__ out_ema)
{
    int i = blockIdx.x * blockDim.x + threadIdx.x;
    float e = ema_w[i] * DECAY_F + OMD_F * be[i];
    out_ema[i] = e;
    out_emb[i] = e / smoothed[i >> 7];
}

// ---------------------------------------------------------------------------
extern "C" void kernel_launch(void* const* d_in, const int* in_sizes, int n_in,
                              void* d_out, int out_size, void* d_ws, size_t ws_size,
                              hipStream_t stream) {
    const float* z   = (const float*)d_in[0];
    const float* emb = (const float*)d_in[1];
    const float* cs  = (const float*)d_in[2];
    const float* ema = (const float*)d_in[3];

    float* out    = (float*)d_out;
    float* o_zq   = out;
    float* o_idx  = o_zq + (size_t)N_ROWS * D_DIM;
    float* o_loss = o_idx + N_ROWS;
    float* o_emb  = o_loss + 1;
    float* o_ncs  = o_emb + K_CODES * D_DIM;
    float* o_ema  = o_ncs + K_CODES;

    float* ws = (float*)d_ws;
    int*            cnt      = (int*)(ws + WS_CNT);
    float*          lacc     = ws + WS_LOSS;
    int*            rcount   = (int*)(ws + WS_RC);
    float*          be       = ws + WS_BE;
    float*          enorm    = ws + WS_ENORM;
    float*          smoothed = ws + WS_SMOOTH;
    int*            cursor   = (int*)(ws + WS_CUR);
    unsigned int*   fidx     = (unsigned int*)(ws + WS_FIDX);
    float*          znorm    = ws + WS_ZNORM;
    unsigned int*   rlist    = (unsigned int*)(ws + WS_RLIST);
    uint4*          cand     = (uint4*)(ws + WS_CAND);
    unsigned int*   bucket   = (unsigned int*)(ws + WS_BUCKET);
    int*            scode    = (int*)(ws + WS_SCODE);
    unsigned short* eimg     = (unsigned short*)(ws + WS_EIMG);

    vq_prep<<<128, 256, 0, stream>>>(emb, ws, enorm, eimg);
    vq_score<<<512, 256, 0, stream>>>(z, eimg, enorm, cand, znorm);
    vq_finish<<<256, 256, 0, stream>>>(cand, znorm, o_idx, fidx, cnt, lacc,
                                       rcount, rlist);
    vq_rescue<<<32, 256, 0, stream>>>(z, emb, enorm, cand, znorm, rcount, rlist,
                                      o_idx, fidx, cnt, lacc);
    vq_zqcopy<<<8192, 256, 0, stream>>>(emb, fidx, o_zq);
    vq_mid<<<1, K_CODES, 0, stream>>>(cs, cnt, lacc, o_ncs, o_loss, smoothed, cursor);
    vq_scatter<<<N_ROWS / 256, 256, 0, stream>>>(fidx, cursor, bucket, scode);
    vq_segsum<<<N_ROWS / SEG_TILE, 128, 0, stream>>>(z, bucket, scode, be);
    vq_fin2<<<K_CODES * D_DIM / 256, 256, 0, stream>>>(ema, be, smoothed, o_emb, o_ema);
}